// Round 9
// baseline (467.373 us; speedup 1.0000x reference)
//
#include <hip/hip_runtime.h>
#include <hip/hip_bf16.h>
#include <stdint.h>

#define HID     128
#define OUTC    10
#define NGRAPH  512
#define NGROUP  128        // writer groups (low 3 bits ~ XCD)
#define PSIZE   256        // nodes per bin
#define CAP     88         // entries per (group,bin) region (mean 32, ~10 sigma)

using bf16x8 = __attribute__((ext_vector_type(8))) short;
using f32x4  = __attribute__((ext_vector_type(4))) float;
using u32x4  = __attribute__((ext_vector_type(4))) uint32_t;

__device__ __forceinline__ short f2bf(float f) {
    __hip_bfloat16 h = __float2bfloat16(f);
    return *reinterpret_cast<short*>(&h);
}
__device__ __forceinline__ float bf2f(short s) {
    union { uint32_t u; float f; } x; x.u = ((uint32_t)(uint16_t)s) << 16; return x.f;
}
__device__ __forceinline__ float bflo(uint32_t v) {
    union { uint32_t u; float f; } x; x.u = v << 16; return x.f;
}
__device__ __forceinline__ float bfhi(uint32_t v) {
    union { uint32_t u; float f; } x; x.u = v & 0xffff0000u; return x.f;
}
__device__ __forceinline__ uint32_t pk2(float lo, float hi) {
    return (uint32_t)(uint16_t)f2bf(lo) | ((uint32_t)(uint16_t)f2bf(hi) << 16);
}

// ---------------------------------------------------------------------------
// int64-vs-int32 layout detection (wave-parallel)
// ---------------------------------------------------------------------------
__global__ void detect64_kernel(const int* __restrict__ ei, int* __restrict__ flag) {
    int lane = threadIdx.x & 63;
    int v = ei[2 * lane + 1];
    unsigned long long b = __ballot(v == 0);
    if (threadIdx.x == 0) *flag = (b == ~0ULL) ? 1 : 0;
}

__device__ __forceinline__ int fetch_idx(const int* __restrict__ p, long j, int f64) {
    return p[f64 ? (j << 1) : j];
}

// ---------------------------------------------------------------------------
// CSR pass A: writer-partitioned bin scatter, 128 writer groups.
// ---------------------------------------------------------------------------
__global__ void __launch_bounds__(256) bin_scatter_kernel(
        const int* __restrict__ ei, const int* __restrict__ flag,
        int* __restrict__ cnt, uint32_t* __restrict__ binned,
        long E, int NBIN, int NBINP) {
    const int group = blockIdx.x & (NGROUP - 1);
    const int f = *flag;
    const long stride = (long)gridDim.x * blockDim.x;
    for (long e = (long)blockIdx.x * blockDim.x + threadIdx.x; e < E; e += stride) {
        int s = fetch_idx(ei, e, f);
        int d = fetch_idx(ei, E + e, f);
        int b = d >> 8;
        int pos = atomicAdd(&cnt[group * NBINP + b], 1);
        if (pos < CAP)
            binned[((size_t)group * NBIN + b) * CAP + pos] =
                (uint32_t)s | ((uint32_t)(d & (PSIZE - 1)) << 20);
    }
}

// ---------------------------------------------------------------------------
// bin totals (sum 128 group counters) + exclusive scan, fused, one block.
// NBIN (391) < 1024 -> single-chunk scan.
// ---------------------------------------------------------------------------
__global__ void __launch_bounds__(1024) binscan_kernel(
        const int* __restrict__ cnt, int* __restrict__ bofs, int NBIN, int NBINP) {
    __shared__ int wsum[16];
    const int tid  = threadIdx.x;
    const int lane = tid & 63;
    const int wid  = tid >> 6;
    int v = 0;
    if (tid < NBIN) {
        for (int g = 0; g < NGROUP; ++g) v += cnt[g * NBINP + tid];
    }
    int inc = v;
#pragma unroll
    for (int d = 1; d < 64; d <<= 1) {
        int t = __shfl_up(inc, d, 64);
        if (lane >= d) inc += t;
    }
    if (lane == 63) wsum[wid] = inc;
    __syncthreads();
    if (wid == 0) {
        int ws = (lane < 16) ? wsum[lane] : 0;
        int winc = ws;
#pragma unroll
        for (int d = 1; d < 16; d <<= 1) {
            int t = __shfl_up(winc, d, 64);
            if (lane >= d) winc += t;
        }
        if (lane < 16) wsum[lane] = winc - ws;
    }
    __syncthreads();
    int excl = wsum[wid] + (inc - v);
    if (tid <= NBIN) bofs[tid] = excl;   // tid >= NBIN: v=0 -> excl = grand total
}

// ---------------------------------------------------------------------------
// CSR pass B: one block per bin; LDS histogram -> scan -> scatter; ofs + dinv.
// ---------------------------------------------------------------------------
__global__ void __launch_bounds__(512) bin_build_kernel(
        const uint32_t* __restrict__ binned, const int* __restrict__ cnt,
        const int* __restrict__ bofs, int* __restrict__ ofs,
        float* __restrict__ dinv, int* __restrict__ col,
        int n, int NBIN, int NBINP, long E) {
    __shared__ int lcnt[PSIZE];
    __shared__ int lofs[PSIZE];
    __shared__ int lrank[PSIZE];
    __shared__ int wtot[4];
    const int b    = blockIdx.x;
    const int v0   = b * PSIZE;
    const int nn   = min(PSIZE, n - v0);
    const int tid  = threadIdx.x;
    const int wv   = tid >> 6;      // 0..7
    const int lane = tid & 63;
    if (tid < PSIZE) { lcnt[tid] = 0; lrank[tid] = 0; }
    __syncthreads();
    for (int sg = wv; sg < NGROUP; sg += 8) {
        const int c = min(cnt[sg * NBINP + b], CAP);
        const uint32_t* __restrict__ src = binned + ((size_t)sg * NBIN + b) * CAP;
        for (int i = lane; i < c; i += 64)
            atomicAdd(&lcnt[src[i] >> 20], 1);
    }
    __syncthreads();
    if (tid < PSIZE) {               // 4-wave two-level scan of lcnt
        int v = lcnt[tid];
        int inc = v;
#pragma unroll
        for (int d = 1; d < 64; d <<= 1) {
            int t = __shfl_up(inc, d, 64);
            if (lane >= d) inc += t;
        }
        if (lane == 63) wtot[wv] = inc;
        lofs[tid] = inc - v;
    }
    __syncthreads();
    if (tid < PSIZE) {
        int add = 0;
#pragma unroll
        for (int k = 0; k < 4; ++k) if (k < wv) add += wtot[k];
        lofs[tid] += add;
    }
    __syncthreads();
    const int base = bofs[b];
    for (int sg = wv; sg < NGROUP; sg += 8) {
        const int c = min(cnt[sg * NBINP + b], CAP);
        const uint32_t* __restrict__ src = binned + ((size_t)sg * NBIN + b) * CAP;
        for (int i = lane; i < c; i += 64) {
            uint32_t v = src[i];
            int dl = (int)(v >> 20);
            int rk = atomicAdd(&lrank[dl], 1);
            col[base + lofs[dl] + rk] = (int)(v & 0xFFFFFu);
        }
    }
    if (tid < nn) {
        ofs[v0 + tid]  = base + lofs[tid];
        dinv[v0 + tid] = rsqrtf((float)lcnt[tid] + 1.0f);
    }
    if (tid == 0 && v0 + nn == n) ofs[n] = (int)E;
}

// ---------------------------------------------------------------------------
// Weight prep: Wt[w] = transpose(W_w) split into bf16 hi + lo planes.
// ---------------------------------------------------------------------------
__global__ void __launch_bounds__(128) wprep_kernel(
        const float* __restrict__ W0, const float* __restrict__ W1,
        const float* __restrict__ W2, short* __restrict__ Wt) {
    const float* W = (blockIdx.x == 0) ? W0 : (blockIdx.x == 1) ? W1 : W2;
    short* hi = Wt + (size_t)blockIdx.x * 2 * HID * HID;
    short* lo = hi + HID * HID;
    __shared__ float Ws[64][129];
    const int t = threadIdx.x;
    for (int half = 0; half < 2; ++half) {
        const int kbase = half * 64;
#pragma unroll
        for (int it = 0; it < 16; ++it) {
            int idx = (t + it * 128) * 4;
            int k = idx >> 7, c = idx & 127;
            float4 v = *(const float4*)(W + (size_t)(kbase + k) * HID + c);
            Ws[k][c] = v.x; Ws[k][c + 1] = v.y; Ws[k][c + 2] = v.z; Ws[k][c + 3] = v.w;
        }
        __syncthreads();
        for (int it = 0; it < 64; ++it) {
            int k2 = t & 63;
            int c  = (t >> 6) + it * 2;
            float w = Ws[k2][c];
            short h = f2bf(w);
            hi[(size_t)c * HID + kbase + k2] = h;
            lo[(size_t)c * HID + kbase + k2] = f2bf(w - bf2f(h));
        }
        __syncthreads();
    }
}

// ---------------------------------------------------------------------------
// hs = bf16( (A @ W) * dinv[:,None] ) — MFMA bf16, LDS-free, split-W hi+lo.
// ---------------------------------------------------------------------------
template<bool AFP32>
__global__ void __launch_bounds__(256) gemm_hs_kernel(
        const void* __restrict__ Ap, const short* __restrict__ Wt,
        const float* __restrict__ dinv, short* __restrict__ hs, int n) {
    const short* __restrict__ Bh = Wt;
    const short* __restrict__ Bl = Wt + HID * HID;
    const int tid = threadIdx.x;
    const int w  = tid >> 6;
    const int l  = tid & 63;
    const int lr = l & 15;
    const int kq = l >> 4;
    const int r0 = blockIdx.x * 128;

    f32x4 acc[8][2] = {};
    const int col0 = w * 32 + lr;
    const int col1 = w * 32 + 16 + lr;

    const float* Af = (const float*)Ap;
    const short* Ab = (const short*)Ap;

#pragma unroll
    for (int ks = 0; ks < 4; ++ks) {
        const int k0 = ks * 32 + kq * 8;
        bf16x8 a[8];
#pragma unroll
        for (int rf = 0; rf < 8; ++rf) {
            int row = r0 + rf * 16 + lr;
            if (row >= n) row = n - 1;
            if (AFP32) {
                const float* ap = Af + (size_t)row * HID + k0;
                float4 f0 = *(const float4*)ap;
                float4 f1 = *(const float4*)(ap + 4);
                bf16x8 tv;
                tv[0] = f2bf(f0.x); tv[1] = f2bf(f0.y); tv[2] = f2bf(f0.z); tv[3] = f2bf(f0.w);
                tv[4] = f2bf(f1.x); tv[5] = f2bf(f1.y); tv[6] = f2bf(f1.z); tv[7] = f2bf(f1.w);
                a[rf] = tv;
            } else {
                a[rf] = *(const bf16x8*)(Ab + (size_t)row * HID + k0);
            }
        }
        bf16x8 bh0 = *(const bf16x8*)(Bh + (size_t)col0 * HID + k0);
        bf16x8 bh1 = *(const bf16x8*)(Bh + (size_t)col1 * HID + k0);
        bf16x8 bl0 = *(const bf16x8*)(Bl + (size_t)col0 * HID + k0);
        bf16x8 bl1 = *(const bf16x8*)(Bl + (size_t)col1 * HID + k0);
#pragma unroll
        for (int rf = 0; rf < 8; ++rf) {
            acc[rf][0] = __builtin_amdgcn_mfma_f32_16x16x32_bf16(a[rf], bh0, acc[rf][0], 0, 0, 0);
            acc[rf][1] = __builtin_amdgcn_mfma_f32_16x16x32_bf16(a[rf], bh1, acc[rf][1], 0, 0, 0);
            acc[rf][0] = __builtin_amdgcn_mfma_f32_16x16x32_bf16(a[rf], bl0, acc[rf][0], 0, 0, 0);
            acc[rf][1] = __builtin_amdgcn_mfma_f32_16x16x32_bf16(a[rf], bl1, acc[rf][1], 0, 0, 0);
        }
    }
#pragma unroll
    for (int rf = 0; rf < 8; ++rf) {
#pragma unroll
        for (int rg = 0; rg < 4; ++rg) {
            int row = r0 + rf * 16 + kq * 4 + rg;
            if (row < n) {
                float dn = dinv[row];
                hs[(size_t)row * HID + col0] = f2bf(acc[rf][0][rg] * dn);
                hs[(size_t)row * HID + col1] = f2bf(acc[rf][1][rg] * dn);
            }
        }
    }
}

// ---------------------------------------------------------------------------
// out[d] = maybe_relu( dinv[d] * (hs[d] + sum_{e->d} hs[src]) + bias )  (bf16)
// One wave per node; 16 lanes per row (dwordx4). Single predicated 16-edge
// chunk loop: every node gets 16 gathers in flight (dead lanes re-read the
// hot col[e0] row). NT col loads + NT output stores keep L2 for hs.
// ---------------------------------------------------------------------------
__device__ __forceinline__ void acc_add(float* acc, u32x4 v) {
    acc[0] += bflo(v.x); acc[1] += bfhi(v.x);
    acc[2] += bflo(v.y); acc[3] += bfhi(v.y);
    acc[4] += bflo(v.z); acc[5] += bfhi(v.z);
    acc[6] += bflo(v.w); acc[7] += bfhi(v.w);
}

__global__ void __launch_bounds__(256) agg_kernel(
        const short* __restrict__ hs, const float* __restrict__ dinv,
        const int* __restrict__ ofs, const int* __restrict__ col,
        const float* __restrict__ bias, short* __restrict__ out,
        int n, int do_relu) {
    int node = blockIdx.x * 4 + (threadIdx.x >> 6);
    if (node >= n) return;
    const int lane = threadIdx.x & 63;
    const int g    = lane >> 4;      // row-group 0..3
    const int sub  = lane & 15;      // 16B chunk within row
    const u32x4* __restrict__ rows = (const u32x4*)hs;   // one row = 16 u32x4

    float acc[8] = {0.f, 0.f, 0.f, 0.f, 0.f, 0.f, 0.f, 0.f};
    if (g == 0) {                    // self term (hs already *dinv)
        u32x4 sv = rows[(size_t)node * 16 + sub];
        acc_add(acc, sv);
    }
    const int e0 = ofs[node], e1 = ofs[node + 1];
    for (int e = e0; e < e1; e += 16) {
        int i0 = e + g;
        int i1 = e + 4 + g;
        int i2 = e + 8 + g;
        int i3 = e + 12 + g;
        int c0 = __builtin_nontemporal_load(col + (i0 < e1 ? i0 : e0));
        int c1 = __builtin_nontemporal_load(col + (i1 < e1 ? i1 : e0));
        int c2 = __builtin_nontemporal_load(col + (i2 < e1 ? i2 : e0));
        int c3 = __builtin_nontemporal_load(col + (i3 < e1 ? i3 : e0));
        u32x4 v0 = rows[(size_t)c0 * 16 + sub];
        u32x4 v1 = rows[(size_t)c1 * 16 + sub];
        u32x4 v2 = rows[(size_t)c2 * 16 + sub];
        u32x4 v3 = rows[(size_t)c3 * 16 + sub];
        if (i0 < e1) acc_add(acc, v0);
        if (i1 < e1) acc_add(acc, v1);
        if (i2 < e1) acc_add(acc, v2);
        if (i3 < e1) acc_add(acc, v3);
    }
#pragma unroll
    for (int i = 0; i < 8; ++i) {    // combine the 4 row-groups
        acc[i] += __shfl_xor(acc[i], 16, 64);
        acc[i] += __shfl_xor(acc[i], 32, 64);
    }
    if (g == 0) {
        const float dn = dinv[node];
        float4 b0 = *(const float4*)(bias + 8 * sub);
        float4 b1 = *(const float4*)(bias + 8 * sub + 4);
        float o0 = fmaf(acc[0], dn, b0.x);
        float o1 = fmaf(acc[1], dn, b0.y);
        float o2 = fmaf(acc[2], dn, b0.z);
        float o3 = fmaf(acc[3], dn, b0.w);
        float o4 = fmaf(acc[4], dn, b1.x);
        float o5 = fmaf(acc[5], dn, b1.y);
        float o6 = fmaf(acc[6], dn, b1.z);
        float o7 = fmaf(acc[7], dn, b1.w);
        if (do_relu) {
            o0 = fmaxf(o0, 0.f); o1 = fmaxf(o1, 0.f);
            o2 = fmaxf(o2, 0.f); o3 = fmaxf(o3, 0.f);
            o4 = fmaxf(o4, 0.f); o5 = fmaxf(o5, 0.f);
            o6 = fmaxf(o6, 0.f); o7 = fmaxf(o7, 0.f);
        }
        u32x4 pk;
        pk.x = pk2(o0, o1); pk.y = pk2(o2, o3);
        pk.z = pk2(o4, o5); pk.w = pk2(o6, o7);
        __builtin_nontemporal_store(pk, (u32x4*)out + (size_t)node * 16 + sub);
    }
}

// ---------------------------------------------------------------------------
// pooling + MLP head
// ---------------------------------------------------------------------------
__global__ void boundary_kernel(const int* __restrict__ batch, const int* __restrict__ flag,
                                int* __restrict__ gstart, int n) {
    int i = blockIdx.x * blockDim.x + threadIdx.x;
    if (i >= n) return;
    int f = *flag;
    int b  = fetch_idx(batch, i, f);
    int bp = (i == 0) ? -1 : fetch_idx(batch, i - 1, f);
    for (int g = bp + 1; g <= b; ++g) gstart[g] = i;
    if (i == n - 1) {
        for (int g = b + 1; g <= NGRAPH; ++g) gstart[g] = n;
    }
}

__global__ void __launch_bounds__(128) pool_kernel(const short* __restrict__ h,
                                                   const int* __restrict__ gstart,
                                                   float* __restrict__ pooled) {
    int g = blockIdx.x, c = threadIdx.x;
    int s = gstart[g], e = gstart[g + 1];
    float acc = 0.f;
    int i = s;
    for (; i + 4 <= e; i += 4) {
        acc += bf2f(h[(size_t)i * HID + c]) + bf2f(h[(size_t)(i + 1) * HID + c])
             + bf2f(h[(size_t)(i + 2) * HID + c]) + bf2f(h[(size_t)(i + 3) * HID + c]);
    }
    for (; i < e; ++i) acc += bf2f(h[(size_t)i * HID + c]);
    float cnt = (float)(e - s);
    pooled[g * HID + c] = acc / fmaxf(cnt, 1.f);
}

__global__ void __launch_bounds__(128) mlp_kernel(
        const float* __restrict__ pooled,
        const float* __restrict__ W1, const float* __restrict__ b1,
        const float* __restrict__ W2, const float* __restrict__ b2,
        float* __restrict__ out) {
    __shared__ float p[HID];
    __shared__ float hid[HID];
    int g = blockIdx.x, c = threadIdx.x;
    p[c] = pooled[g * HID + c];
    __syncthreads();
    float a = b1[c];
#pragma unroll 8
    for (int k = 0; k < HID; ++k) a = fmaf(p[k], W1[k * HID + c], a);
    hid[c] = fmaxf(a, 0.f);
    __syncthreads();
    if (c < OUTC) {
        float o = b2[c];
#pragma unroll 8
        for (int k = 0; k < HID; ++k) o = fmaf(hid[k], W2[k * OUTC + c], o);
        out[g * OUTC + c] = o;
    }
}

// ---------------------------------------------------------------------------
extern "C" void kernel_launch(void* const* d_in, const int* in_sizes, int n_in,
                              void* d_out, int out_size, void* d_ws, size_t ws_size,
                              hipStream_t stream) {
    const float* x   = (const float*)d_in[0];
    const int*   ei  = (const int*)d_in[1];
    const int*   bat = (const int*)d_in[2];
    const float* Wc0 = (const float*)d_in[3];
    const float* bc0 = (const float*)d_in[4];
    const float* Wc1 = (const float*)d_in[5];
    const float* bc1 = (const float*)d_in[6];
    const float* Wc2 = (const float*)d_in[7];
    const float* bc2 = (const float*)d_in[8];
    const float* W1  = (const float*)d_in[9];
    const float* b1  = (const float*)d_in[10];
    const float* W2  = (const float*)d_in[11];
    const float* b2  = (const float*)d_in[12];
    float* out = (float*)d_out;

    const int  n = in_sizes[0] / HID;             // 100000 (< 2^20)
    const long E = in_sizes[1] / 2;
    const int  NBIN  = (n + PSIZE - 1) / PSIZE;   // 391
    const int  NBINP = (NBIN + 15) & ~15;         // 400: per-group counters line-aligned

    char* w = (char*)d_ws;
    size_t off = 0;
    auto carve = [&](size_t bytes) {
        void* p = w + off;
        off += (bytes + 255) & ~(size_t)255;
        return p;
    };
    int*   flag    = (int*)carve(4);
    int*   cnt     = (int*)carve((size_t)NGROUP * NBINP * 4);
    int*   bofs    = (int*)carve((size_t)(NBIN + 1) * 4);
    int*   ofs     = (int*)carve((size_t)(n + 1) * 4);
    float* dinv    = (float*)carve((size_t)n * 4);
    int*   gstart  = (int*)carve((NGRAPH + 1) * 4);
    int*   col     = (int*)carve((size_t)E * 4);
    short* Wt      = (short*)carve((size_t)3 * 2 * HID * HID * 2);
    short* hs      = (short*)carve((size_t)n * HID * 2);
    short* h       = (short*)carve((size_t)n * HID * 2);
    float* pooled  = (float*)carve((size_t)NGRAPH * HID * 4);
    uint32_t* binned = (uint32_t*)h;  // 128*391*88*4 = 17.6 MB <= 25.6 MB (h), dead before h written

    hipMemsetAsync(cnt, 0, (size_t)NGROUP * NBINP * 4, stream);

    detect64_kernel<<<1, 64, 0, stream>>>(ei, flag);

    bin_scatter_kernel<<<2048, 256, 0, stream>>>(ei, flag, cnt, binned, E, NBIN, NBINP);
    binscan_kernel<<<1, 1024, 0, stream>>>(cnt, bofs, NBIN, NBINP);
    bin_build_kernel<<<NBIN, 512, 0, stream>>>(binned, cnt, bofs, ofs, dinv, col,
                                               n, NBIN, NBINP, E);
    wprep_kernel<<<3, 128, 0, stream>>>(Wc0, Wc1, Wc2, Wt);

    const int gb = (n + 127) / 128;
    const int ab = (n + 3) / 4;
    const size_t WSTRIDE = (size_t)2 * HID * HID;
    // layer 0
    gemm_hs_kernel<true><<<gb, 256, 0, stream>>>(x, Wt, dinv, hs, n);
    agg_kernel<<<ab, 256, 0, stream>>>(hs, dinv, ofs, col, bc0, h, n, 1);
    // layer 1
    gemm_hs_kernel<false><<<gb, 256, 0, stream>>>(h, Wt + WSTRIDE, dinv, hs, n);
    agg_kernel<<<ab, 256, 0, stream>>>(hs, dinv, ofs, col, bc1, h, n, 1);
    // layer 2 (no relu)
    gemm_hs_kernel<false><<<gb, 256, 0, stream>>>(h, Wt + 2 * WSTRIDE, dinv, hs, n);
    agg_kernel<<<ab, 256, 0, stream>>>(hs, dinv, ofs, col, bc2, h, n, 0);

    boundary_kernel<<<(n + 255) / 256, 256, 0, stream>>>(bat, flag, gstart, n);
    pool_kernel<<<NGRAPH, 128, 0, stream>>>(h, gstart, pooled);
    mlp_kernel<<<NGRAPH, 128, 0, stream>>>(pooled, W1, b1, W2, b2, out);
}

// Round 10
// 429.807 us; speedup vs baseline: 1.0874x; 1.0874x over previous
//
#include <hip/hip_runtime.h>
#include <hip/hip_bf16.h>
#include <stdint.h>

#define HID     128
#define OUTC    10
#define NGRAPH  512
#define NGROUP  64         // writer groups (low 3 bits ~ XCD)  [round-6/7 validated]
#define PSIZE   256        // nodes per bin
#define CAP     160        // entries per (group,bin) region (mean 64, ~12 sigma)

using bf16x8 = __attribute__((ext_vector_type(8))) short;
using f32x4  = __attribute__((ext_vector_type(4))) float;
using u32x4  = __attribute__((ext_vector_type(4))) uint32_t;

__device__ __forceinline__ short f2bf(float f) {
    __hip_bfloat16 h = __float2bfloat16(f);
    return *reinterpret_cast<short*>(&h);
}
__device__ __forceinline__ float bf2f(short s) {
    union { uint32_t u; float f; } x; x.u = ((uint32_t)(uint16_t)s) << 16; return x.f;
}
__device__ __forceinline__ float bflo(uint32_t v) {
    union { uint32_t u; float f; } x; x.u = v << 16; return x.f;
}
__device__ __forceinline__ float bfhi(uint32_t v) {
    union { uint32_t u; float f; } x; x.u = v & 0xffff0000u; return x.f;
}
__device__ __forceinline__ uint32_t pk2(float lo, float hi) {
    return (uint32_t)(uint16_t)f2bf(lo) | ((uint32_t)(uint16_t)f2bf(hi) << 16);
}

// ---------------------------------------------------------------------------
// int64-vs-int32 layout detection (wave-parallel)
// ---------------------------------------------------------------------------
__global__ void detect64_kernel(const int* __restrict__ ei, int* __restrict__ flag) {
    int lane = threadIdx.x & 63;
    int v = ei[2 * lane + 1];
    unsigned long long b = __ballot(v == 0);
    if (threadIdx.x == 0) *flag = (b == ~0ULL) ? 1 : 0;
}

__device__ __forceinline__ int fetch_idx(const int* __restrict__ p, long j, int f64) {
    return p[f64 ? (j << 1) : j];
}

// ---------------------------------------------------------------------------
// CSR pass A: writer-partitioned bin scatter, 64 writer groups.
// ---------------------------------------------------------------------------
__global__ void __launch_bounds__(256) bin_scatter_kernel(
        const int* __restrict__ ei, const int* __restrict__ flag,
        int* __restrict__ cnt, uint32_t* __restrict__ binned,
        long E, int NBIN, int NBINP) {
    const int group = blockIdx.x & (NGROUP - 1);
    const int f = *flag;
    const long stride = (long)gridDim.x * blockDim.x;
    for (long e = (long)blockIdx.x * blockDim.x + threadIdx.x; e < E; e += stride) {
        int s = fetch_idx(ei, e, f);
        int d = fetch_idx(ei, E + e, f);
        int b = d >> 8;
        int pos = atomicAdd(&cnt[group * NBINP + b], 1);
        if (pos < CAP)
            binned[((size_t)group * NBIN + b) * CAP + pos] =
                (uint32_t)s | ((uint32_t)(d & (PSIZE - 1)) << 20);
    }
}

// ---------------------------------------------------------------------------
// bin totals (sum 64 group counters) + exclusive scan, fused, one block.
// ---------------------------------------------------------------------------
__global__ void __launch_bounds__(1024) binscan_kernel(
        const int* __restrict__ cnt, int* __restrict__ bofs, int NBIN, int NBINP) {
    __shared__ int wsum[16];
    const int tid  = threadIdx.x;
    const int lane = tid & 63;
    const int wid  = tid >> 6;
    int v = 0;
    if (tid < NBIN) {
        for (int g = 0; g < NGROUP; ++g) v += cnt[g * NBINP + tid];
    }
    int inc = v;
#pragma unroll
    for (int d = 1; d < 64; d <<= 1) {
        int t = __shfl_up(inc, d, 64);
        if (lane >= d) inc += t;
    }
    if (lane == 63) wsum[wid] = inc;
    __syncthreads();
    if (wid == 0) {
        int ws = (lane < 16) ? wsum[lane] : 0;
        int winc = ws;
#pragma unroll
        for (int d = 1; d < 16; d <<= 1) {
            int t = __shfl_up(winc, d, 64);
            if (lane >= d) winc += t;
        }
        if (lane < 16) wsum[lane] = winc - ws;
    }
    __syncthreads();
    int excl = wsum[wid] + (inc - v);
    if (tid <= NBIN) bofs[tid] = excl;   // tid >= NBIN: v=0 -> excl = grand total
}

// ---------------------------------------------------------------------------
// CSR pass B: one block per bin; LDS histogram -> scan -> scatter; ofs + dinv.
// ---------------------------------------------------------------------------
__global__ void __launch_bounds__(512) bin_build_kernel(
        const uint32_t* __restrict__ binned, const int* __restrict__ cnt,
        const int* __restrict__ bofs, int* __restrict__ ofs,
        float* __restrict__ dinv, int* __restrict__ col,
        int n, int NBIN, int NBINP, long E) {
    __shared__ int lcnt[PSIZE];
    __shared__ int lofs[PSIZE];
    __shared__ int lrank[PSIZE];
    __shared__ int wtot[4];
    const int b    = blockIdx.x;
    const int v0   = b * PSIZE;
    const int nn   = min(PSIZE, n - v0);
    const int tid  = threadIdx.x;
    const int wv   = tid >> 6;      // 0..7
    const int lane = tid & 63;
    if (tid < PSIZE) { lcnt[tid] = 0; lrank[tid] = 0; }
    __syncthreads();
    for (int sg = wv; sg < NGROUP; sg += 8) {
        const int c = min(cnt[sg * NBINP + b], CAP);
        const uint32_t* __restrict__ src = binned + ((size_t)sg * NBIN + b) * CAP;
        for (int i = lane; i < c; i += 64)
            atomicAdd(&lcnt[src[i] >> 20], 1);
    }
    __syncthreads();
    if (tid < PSIZE) {               // 4-wave two-level scan of lcnt
        int v = lcnt[tid];
        int inc = v;
#pragma unroll
        for (int d = 1; d < 64; d <<= 1) {
            int t = __shfl_up(inc, d, 64);
            if (lane >= d) inc += t;
        }
        if (lane == 63) wtot[wv] = inc;
        lofs[tid] = inc - v;
    }
    __syncthreads();
    if (tid < PSIZE) {
        int add = 0;
#pragma unroll
        for (int k = 0; k < 4; ++k) if (k < wv) add += wtot[k];
        lofs[tid] += add;
    }
    __syncthreads();
    const int base = bofs[b];
    for (int sg = wv; sg < NGROUP; sg += 8) {
        const int c = min(cnt[sg * NBINP + b], CAP);
        const uint32_t* __restrict__ src = binned + ((size_t)sg * NBIN + b) * CAP;
        for (int i = lane; i < c; i += 64) {
            uint32_t v = src[i];
            int dl = (int)(v >> 20);
            int rk = atomicAdd(&lrank[dl], 1);
            col[base + lofs[dl] + rk] = (int)(v & 0xFFFFFu);
        }
    }
    if (tid < nn) {
        ofs[v0 + tid]  = base + lofs[tid];
        dinv[v0 + tid] = rsqrtf((float)lcnt[tid] + 1.0f);
    }
    if (tid == 0 && v0 + nn == n) ofs[n] = (int)E;
}

// ---------------------------------------------------------------------------
// Weight prep: Wt[w] = transpose(W_w) split into bf16 hi + lo planes.
// ---------------------------------------------------------------------------
__global__ void __launch_bounds__(128) wprep_kernel(
        const float* __restrict__ W0, const float* __restrict__ W1,
        const float* __restrict__ W2, short* __restrict__ Wt) {
    const float* W = (blockIdx.x == 0) ? W0 : (blockIdx.x == 1) ? W1 : W2;
    short* hi = Wt + (size_t)blockIdx.x * 2 * HID * HID;
    short* lo = hi + HID * HID;
    __shared__ float Ws[64][129];
    const int t = threadIdx.x;
    for (int half = 0; half < 2; ++half) {
        const int kbase = half * 64;
#pragma unroll
        for (int it = 0; it < 16; ++it) {
            int idx = (t + it * 128) * 4;
            int k = idx >> 7, c = idx & 127;
            float4 v = *(const float4*)(W + (size_t)(kbase + k) * HID + c);
            Ws[k][c] = v.x; Ws[k][c + 1] = v.y; Ws[k][c + 2] = v.z; Ws[k][c + 3] = v.w;
        }
        __syncthreads();
        for (int it = 0; it < 64; ++it) {
            int k2 = t & 63;
            int c  = (t >> 6) + it * 2;
            float w = Ws[k2][c];
            short h = f2bf(w);
            hi[(size_t)c * HID + kbase + k2] = h;
            lo[(size_t)c * HID + kbase + k2] = f2bf(w - bf2f(h));
        }
        __syncthreads();
    }
}

// ---------------------------------------------------------------------------
// hs = bf16( (A @ W) * dinv[:,None] ) — MFMA bf16, LDS-free, split-W hi+lo.
// ---------------------------------------------------------------------------
template<bool AFP32>
__global__ void __launch_bounds__(256) gemm_hs_kernel(
        const void* __restrict__ Ap, const short* __restrict__ Wt,
        const float* __restrict__ dinv, short* __restrict__ hs, int n) {
    const short* __restrict__ Bh = Wt;
    const short* __restrict__ Bl = Wt + HID * HID;
    const int tid = threadIdx.x;
    const int w  = tid >> 6;
    const int l  = tid & 63;
    const int lr = l & 15;
    const int kq = l >> 4;
    const int r0 = blockIdx.x * 128;

    f32x4 acc[8][2] = {};
    const int col0 = w * 32 + lr;
    const int col1 = w * 32 + 16 + lr;

    const float* Af = (const float*)Ap;
    const short* Ab = (const short*)Ap;

#pragma unroll
    for (int ks = 0; ks < 4; ++ks) {
        const int k0 = ks * 32 + kq * 8;
        bf16x8 a[8];
#pragma unroll
        for (int rf = 0; rf < 8; ++rf) {
            int row = r0 + rf * 16 + lr;
            if (row >= n) row = n - 1;
            if (AFP32) {
                const float* ap = Af + (size_t)row * HID + k0;
                float4 f0 = *(const float4*)ap;
                float4 f1 = *(const float4*)(ap + 4);
                bf16x8 tv;
                tv[0] = f2bf(f0.x); tv[1] = f2bf(f0.y); tv[2] = f2bf(f0.z); tv[3] = f2bf(f0.w);
                tv[4] = f2bf(f1.x); tv[5] = f2bf(f1.y); tv[6] = f2bf(f1.z); tv[7] = f2bf(f1.w);
                a[rf] = tv;
            } else {
                a[rf] = *(const bf16x8*)(Ab + (size_t)row * HID + k0);
            }
        }
        bf16x8 bh0 = *(const bf16x8*)(Bh + (size_t)col0 * HID + k0);
        bf16x8 bh1 = *(const bf16x8*)(Bh + (size_t)col1 * HID + k0);
        bf16x8 bl0 = *(const bf16x8*)(Bl + (size_t)col0 * HID + k0);
        bf16x8 bl1 = *(const bf16x8*)(Bl + (size_t)col1 * HID + k0);
#pragma unroll
        for (int rf = 0; rf < 8; ++rf) {
            acc[rf][0] = __builtin_amdgcn_mfma_f32_16x16x32_bf16(a[rf], bh0, acc[rf][0], 0, 0, 0);
            acc[rf][1] = __builtin_amdgcn_mfma_f32_16x16x32_bf16(a[rf], bh1, acc[rf][1], 0, 0, 0);
            acc[rf][0] = __builtin_amdgcn_mfma_f32_16x16x32_bf16(a[rf], bl0, acc[rf][0], 0, 0, 0);
            acc[rf][1] = __builtin_amdgcn_mfma_f32_16x16x32_bf16(a[rf], bl1, acc[rf][1], 0, 0, 0);
        }
    }
#pragma unroll
    for (int rf = 0; rf < 8; ++rf) {
#pragma unroll
        for (int rg = 0; rg < 4; ++rg) {
            int row = r0 + rf * 16 + kq * 4 + rg;
            if (row < n) {
                float dn = dinv[row];
                hs[(size_t)row * HID + col0] = f2bf(acc[rf][0][rg] * dn);
                hs[(size_t)row * HID + col1] = f2bf(acc[rf][1][rg] * dn);
            }
        }
    }
}

// ---------------------------------------------------------------------------
// out[d] = maybe_relu( dinv[d] * (hs[d] + sum_{e->d} hs[src]) + bias )  (bf16)
// One wave per node; 16 lanes per row (dwordx4), 4 rows per gather instr,
// up to 16 rows in flight (ladder 16/4/1). [round-7 validated: 66 us]
// ---------------------------------------------------------------------------
__device__ __forceinline__ void acc_add(float* acc, u32x4 v) {
    acc[0] += bflo(v.x); acc[1] += bfhi(v.x);
    acc[2] += bflo(v.y); acc[3] += bfhi(v.y);
    acc[4] += bflo(v.z); acc[5] += bfhi(v.z);
    acc[6] += bflo(v.w); acc[7] += bfhi(v.w);
}

__global__ void __launch_bounds__(256) agg_kernel(
        const short* __restrict__ hs, const float* __restrict__ dinv,
        const int* __restrict__ ofs, const int* __restrict__ col,
        const float* __restrict__ bias, short* __restrict__ out,
        int n, int do_relu) {
    int node = blockIdx.x * 4 + (threadIdx.x >> 6);
    if (node >= n) return;
    const int lane = threadIdx.x & 63;
    const int g    = lane >> 4;      // row-group 0..3
    const int sub  = lane & 15;      // 16B chunk within row
    const u32x4* __restrict__ rows = (const u32x4*)hs;   // one row = 16 u32x4

    float acc[8] = {0.f, 0.f, 0.f, 0.f, 0.f, 0.f, 0.f, 0.f};
    if (g == 0) {                    // self term (hs already *dinv)
        u32x4 sv = rows[(size_t)node * 16 + sub];
        acc_add(acc, sv);
    }
    const int e0 = ofs[node], e1 = ofs[node + 1];
    int e = e0;
    for (; e + 16 <= e1; e += 16) {  // 16 rows in flight
        int c0 = col[e + g];
        int c1 = col[e + 4 + g];
        int c2 = col[e + 8 + g];
        int c3 = col[e + 12 + g];
        u32x4 v0 = rows[(size_t)c0 * 16 + sub];
        u32x4 v1 = rows[(size_t)c1 * 16 + sub];
        u32x4 v2 = rows[(size_t)c2 * 16 + sub];
        u32x4 v3 = rows[(size_t)c3 * 16 + sub];
        acc_add(acc, v0); acc_add(acc, v1); acc_add(acc, v2); acc_add(acc, v3);
    }
    for (; e + 4 <= e1; e += 4) {
        int c0 = col[e + g];
        u32x4 v0 = rows[(size_t)c0 * 16 + sub];
        acc_add(acc, v0);
    }
    if (e + g < e1) {                // tail (<4 edges): one row per live group
        int c0 = col[e + g];
        u32x4 v0 = rows[(size_t)c0 * 16 + sub];
        acc_add(acc, v0);
    }
#pragma unroll
    for (int i = 0; i < 8; ++i) {    // combine the 4 row-groups
        acc[i] += __shfl_xor(acc[i], 16, 64);
        acc[i] += __shfl_xor(acc[i], 32, 64);
    }
    if (g == 0) {
        const float dn = dinv[node];
        float4 b0 = *(const float4*)(bias + 8 * sub);
        float4 b1 = *(const float4*)(bias + 8 * sub + 4);
        float o0 = fmaf(acc[0], dn, b0.x);
        float o1 = fmaf(acc[1], dn, b0.y);
        float o2 = fmaf(acc[2], dn, b0.z);
        float o3 = fmaf(acc[3], dn, b0.w);
        float o4 = fmaf(acc[4], dn, b1.x);
        float o5 = fmaf(acc[5], dn, b1.y);
        float o6 = fmaf(acc[6], dn, b1.z);
        float o7 = fmaf(acc[7], dn, b1.w);
        if (do_relu) {
            o0 = fmaxf(o0, 0.f); o1 = fmaxf(o1, 0.f);
            o2 = fmaxf(o2, 0.f); o3 = fmaxf(o3, 0.f);
            o4 = fmaxf(o4, 0.f); o5 = fmaxf(o5, 0.f);
            o6 = fmaxf(o6, 0.f); o7 = fmaxf(o7, 0.f);
        }
        u32x4 pk;
        pk.x = pk2(o0, o1); pk.y = pk2(o2, o3);
        pk.z = pk2(o4, o5); pk.w = pk2(o6, o7);
        ((u32x4*)out)[(size_t)node * 16 + sub] = pk;
    }
}

// ---------------------------------------------------------------------------
// head: boundary detect, then fused mean-pool + MLP (one block per graph)
// ---------------------------------------------------------------------------
__global__ void boundary_kernel(const int* __restrict__ batch, const int* __restrict__ flag,
                                int* __restrict__ gstart, int n) {
    int i = blockIdx.x * blockDim.x + threadIdx.x;
    if (i >= n) return;
    int f = *flag;
    int b  = fetch_idx(batch, i, f);
    int bp = (i == 0) ? -1 : fetch_idx(batch, i - 1, f);
    for (int g = bp + 1; g <= b; ++g) gstart[g] = i;
    if (i == n - 1) {
        for (int g = b + 1; g <= NGRAPH; ++g) gstart[g] = n;
    }
}

__global__ void __launch_bounds__(128) pool_mlp_kernel(
        const short* __restrict__ h, const int* __restrict__ gstart,
        const float* __restrict__ W1, const float* __restrict__ b1,
        const float* __restrict__ W2, const float* __restrict__ b2,
        float* __restrict__ out) {
    __shared__ float p[HID];
    __shared__ float hid[HID];
    int g = blockIdx.x, c = threadIdx.x;
    int s = gstart[g], e = gstart[g + 1];
    float acc = 0.f;
    int i = s;
    for (; i + 4 <= e; i += 4) {
        acc += bf2f(h[(size_t)i * HID + c]) + bf2f(h[(size_t)(i + 1) * HID + c])
             + bf2f(h[(size_t)(i + 2) * HID + c]) + bf2f(h[(size_t)(i + 3) * HID + c]);
    }
    for (; i < e; ++i) acc += bf2f(h[(size_t)i * HID + c]);
    p[c] = acc / fmaxf((float)(e - s), 1.f);
    __syncthreads();
    float a = b1[c];
#pragma unroll 8
    for (int k = 0; k < HID; ++k) a = fmaf(p[k], W1[k * HID + c], a);
    hid[c] = fmaxf(a, 0.f);
    __syncthreads();
    if (c < OUTC) {
        float o = b2[c];
#pragma unroll 8
        for (int k = 0; k < HID; ++k) o = fmaf(hid[k], W2[k * OUTC + c], o);
        out[g * OUTC + c] = o;
    }
}

// ---------------------------------------------------------------------------
extern "C" void kernel_launch(void* const* d_in, const int* in_sizes, int n_in,
                              void* d_out, int out_size, void* d_ws, size_t ws_size,
                              hipStream_t stream) {
    const float* x   = (const float*)d_in[0];
    const int*   ei  = (const int*)d_in[1];
    const int*   bat = (const int*)d_in[2];
    const float* Wc0 = (const float*)d_in[3];
    const float* bc0 = (const float*)d_in[4];
    const float* Wc1 = (const float*)d_in[5];
    const float* bc1 = (const float*)d_in[6];
    const float* Wc2 = (const float*)d_in[7];
    const float* bc2 = (const float*)d_in[8];
    const float* W1  = (const float*)d_in[9];
    const float* b1  = (const float*)d_in[10];
    const float* W2  = (const float*)d_in[11];
    const float* b2  = (const float*)d_in[12];
    float* out = (float*)d_out;

    const int  n = in_sizes[0] / HID;             // 100000 (< 2^20)
    const long E = in_sizes[1] / 2;
    const int  NBIN  = (n + PSIZE - 1) / PSIZE;   // 391
    const int  NBINP = (NBIN + 15) & ~15;         // 400: per-group counters line-aligned

    char* w = (char*)d_ws;
    size_t off = 0;
    auto carve = [&](size_t bytes) {
        void* p = w + off;
        off += (bytes + 255) & ~(size_t)255;
        return p;
    };
    int*   flag    = (int*)carve(4);
    int*   cnt     = (int*)carve((size_t)NGROUP * NBINP * 4);
    int*   bofs    = (int*)carve((size_t)(NBIN + 1) * 4);
    int*   ofs     = (int*)carve((size_t)(n + 1) * 4);
    float* dinv    = (float*)carve((size_t)n * 4);
    int*   gstart  = (int*)carve((NGRAPH + 1) * 4);
    int*   col     = (int*)carve((size_t)E * 4);
    short* Wt      = (short*)carve((size_t)3 * 2 * HID * HID * 2);
    short* hs      = (short*)carve((size_t)n * HID * 2);
    short* h       = (short*)carve((size_t)n * HID * 2);
    uint32_t* binned = (uint32_t*)h;  // 64*391*160*4 = 16.0 MB <= 25.6 MB (h), dead before h written

    hipMemsetAsync(cnt, 0, (size_t)NGROUP * NBINP * 4, stream);

    detect64_kernel<<<1, 64, 0, stream>>>(ei, flag);
    wprep_kernel<<<3, 128, 0, stream>>>(Wc0, Wc1, Wc2, Wt);
    boundary_kernel<<<(n + 255) / 256, 256, 0, stream>>>(bat, flag, gstart, n);

    bin_scatter_kernel<<<2048, 256, 0, stream>>>(ei, flag, cnt, binned, E, NBIN, NBINP);
    binscan_kernel<<<1, 1024, 0, stream>>>(cnt, bofs, NBIN, NBINP);
    bin_build_kernel<<<NBIN, 512, 0, stream>>>(binned, cnt, bofs, ofs, dinv, col,
                                               n, NBIN, NBINP, E);

    const int gb = (n + 127) / 128;
    const int ab = (n + 3) / 4;
    const size_t WSTRIDE = (size_t)2 * HID * HID;
    // layer 0
    gemm_hs_kernel<true><<<gb, 256, 0, stream>>>(x, Wt, dinv, hs, n);
    agg_kernel<<<ab, 256, 0, stream>>>(hs, dinv, ofs, col, bc0, h, n, 1);
    // layer 1
    gemm_hs_kernel<false><<<gb, 256, 0, stream>>>(h, Wt + WSTRIDE, dinv, hs, n);
    agg_kernel<<<ab, 256, 0, stream>>>(hs, dinv, ofs, col, bc1, h, n, 1);
    // layer 2 (no relu)
    gemm_hs_kernel<false><<<gb, 256, 0, stream>>>(h, Wt + 2 * WSTRIDE, dinv, hs, n);
    agg_kernel<<<ab, 256, 0, stream>>>(hs, dinv, ofs, col, bc2, h, n, 0);

    pool_mlp_kernel<<<NGRAPH, 128, 0, stream>>>(h, gstart, W1, b1, W2, b2, out);
}

// Round 11
// 417.357 us; speedup vs baseline: 1.1198x; 1.0298x over previous
//
#include <hip/hip_runtime.h>
#include <hip/hip_bf16.h>
#include <stdint.h>

#define HID     128
#define OUTC    10
#define NGRAPH  512
#define NGROUP  64         // writer groups (low 3 bits ~ XCD)  [round-6/7 validated]
#define PSIZE   256        // nodes per bin
#define CAP     160        // entries per (group,bin) region (mean 64, ~12 sigma)

using bf16x8 = __attribute__((ext_vector_type(8))) short;
using f32x4  = __attribute__((ext_vector_type(4))) float;
using u32x4  = __attribute__((ext_vector_type(4))) uint32_t;

__device__ __forceinline__ short f2bf(float f) {
    __hip_bfloat16 h = __float2bfloat16(f);
    return *reinterpret_cast<short*>(&h);
}
__device__ __forceinline__ float bf2f(short s) {
    union { uint32_t u; float f; } x; x.u = ((uint32_t)(uint16_t)s) << 16; return x.f;
}
__device__ __forceinline__ float bflo(uint32_t v) {
    union { uint32_t u; float f; } x; x.u = v << 16; return x.f;
}
__device__ __forceinline__ float bfhi(uint32_t v) {
    union { uint32_t u; float f; } x; x.u = v & 0xffff0000u; return x.f;
}
__device__ __forceinline__ uint32_t pk2(float lo, float hi) {
    return (uint32_t)(uint16_t)f2bf(lo) | ((uint32_t)(uint16_t)f2bf(hi) << 16);
}

// Inline int64-vs-int32 layout detection: for int32 edge_index the odd words
// are random node ids (P(all 64 == 0) ~ 0); for little-endian int64 < 2^31
// they are all zero. ei lines are L2-hot after the first wave touches them.
__device__ __forceinline__ int detect_f64(const int* __restrict__ ei) {
    int lane = threadIdx.x & 63;
    int v = ei[2 * lane + 1];
    unsigned long long b = __ballot(v == 0);
    return (b == ~0ULL) ? 1 : 0;
}

__device__ __forceinline__ int fetch_idx(const int* __restrict__ p, long j, int f64) {
    return p[f64 ? (j << 1) : j];
}

// ---------------------------------------------------------------------------
// prep: blocks 0-2 -> weight transpose+split; next blocks -> zero cnt;
// remaining blocks -> graph boundary detection. One dispatch.
// ---------------------------------------------------------------------------
__global__ void __launch_bounds__(256) prep_kernel(
        const int* __restrict__ ei, const int* __restrict__ batch,
        const float* __restrict__ W0, const float* __restrict__ W1,
        const float* __restrict__ W2, short* __restrict__ Wt,
        int* __restrict__ cnt, int cntN, int* __restrict__ gstart, int n) {
    __shared__ float Ws[64][129];
    int bid = blockIdx.x;
    const int tid = threadIdx.x;

    if (bid < 3) {                                   // ---- weight prep (256 thr)
        const float* W = (bid == 0) ? W0 : (bid == 1) ? W1 : W2;
        short* hi = Wt + (size_t)bid * 2 * HID * HID;
        short* lo = hi + HID * HID;
        for (int half = 0; half < 2; ++half) {
            const int kbase = half * 64;
#pragma unroll
            for (int it = 0; it < 8; ++it) {         // 2048 float4 loads
                int idx = (tid + it * 256) * 4;
                int k = idx >> 7, c = idx & 127;
                float4 v = *(const float4*)(W + (size_t)(kbase + k) * HID + c);
                Ws[k][c] = v.x; Ws[k][c + 1] = v.y; Ws[k][c + 2] = v.z; Ws[k][c + 3] = v.w;
            }
            __syncthreads();
            const int k2 = tid & 63;
            const int cb = tid >> 6;                 // 0..3
#pragma unroll
            for (int it = 0; it < 32; ++it) {        // transposed writes
                int c = cb + it * 4;
                float w = Ws[k2][c];
                short h = f2bf(w);
                hi[(size_t)c * HID + kbase + k2] = h;
                lo[(size_t)c * HID + kbase + k2] = f2bf(w - bf2f(h));
            }
            __syncthreads();
        }
        return;
    }
    bid -= 3;
    const int nzb = (cntN + 255) / 256;
    if (bid < nzb) {                                 // ---- zero scatter counters
        int i = bid * 256 + tid;
        if (i < cntN) cnt[i] = 0;
        return;
    }
    bid -= nzb;
    // ---- boundary detection (batch sorted)
    const int f = detect_f64(ei);
    int i = bid * 256 + tid;
    if (i >= n) return;
    int b  = fetch_idx(batch, i, f);
    int bp = (i == 0) ? -1 : fetch_idx(batch, i - 1, f);
    for (int g = bp + 1; g <= b; ++g) gstart[g] = i;
    if (i == n - 1) {
        for (int g = b + 1; g <= NGRAPH; ++g) gstart[g] = n;
    }
}

// ---------------------------------------------------------------------------
// CSR pass A: writer-partitioned bin scatter, 64 writer groups.
// ---------------------------------------------------------------------------
__global__ void __launch_bounds__(256) bin_scatter_kernel(
        const int* __restrict__ ei, int* __restrict__ cnt,
        uint32_t* __restrict__ binned, long E, int NBIN, int NBINP) {
    const int group = blockIdx.x & (NGROUP - 1);
    const int f = detect_f64(ei);
    const long stride = (long)gridDim.x * blockDim.x;
    for (long e = (long)blockIdx.x * blockDim.x + threadIdx.x; e < E; e += stride) {
        int s = fetch_idx(ei, e, f);
        int d = fetch_idx(ei, E + e, f);
        int b = d >> 8;
        int pos = atomicAdd(&cnt[group * NBINP + b], 1);
        if (pos < CAP)
            binned[((size_t)group * NBIN + b) * CAP + pos] =
                (uint32_t)s | ((uint32_t)(d & (PSIZE - 1)) << 20);
    }
}

// ---------------------------------------------------------------------------
// bin totals (sum 64 group counters) + exclusive scan, fused, one block.
// ---------------------------------------------------------------------------
__global__ void __launch_bounds__(1024) binscan_kernel(
        const int* __restrict__ cnt, int* __restrict__ bofs, int NBIN, int NBINP) {
    __shared__ int wsum[16];
    const int tid  = threadIdx.x;
    const int lane = tid & 63;
    const int wid  = tid >> 6;
    int v = 0;
    if (tid < NBIN) {
        for (int g = 0; g < NGROUP; ++g) v += cnt[g * NBINP + tid];
    }
    int inc = v;
#pragma unroll
    for (int d = 1; d < 64; d <<= 1) {
        int t = __shfl_up(inc, d, 64);
        if (lane >= d) inc += t;
    }
    if (lane == 63) wsum[wid] = inc;
    __syncthreads();
    if (wid == 0) {
        int ws = (lane < 16) ? wsum[lane] : 0;
        int winc = ws;
#pragma unroll
        for (int d = 1; d < 16; d <<= 1) {
            int t = __shfl_up(winc, d, 64);
            if (lane >= d) winc += t;
        }
        if (lane < 16) wsum[lane] = winc - ws;
    }
    __syncthreads();
    int excl = wsum[wid] + (inc - v);
    if (tid <= NBIN) bofs[tid] = excl;   // tid >= NBIN: v=0 -> excl = grand total
}

// ---------------------------------------------------------------------------
// CSR pass B: one block per bin; LDS histogram -> scan -> scatter; ofs + dinv.
// ---------------------------------------------------------------------------
__global__ void __launch_bounds__(512) bin_build_kernel(
        const uint32_t* __restrict__ binned, const int* __restrict__ cnt,
        const int* __restrict__ bofs, int* __restrict__ ofs,
        float* __restrict__ dinv, int* __restrict__ col,
        int n, int NBIN, int NBINP, long E) {
    __shared__ int lcnt[PSIZE];
    __shared__ int lofs[PSIZE];
    __shared__ int lrank[PSIZE];
    __shared__ int wtot[4];
    const int b    = blockIdx.x;
    const int v0   = b * PSIZE;
    const int nn   = min(PSIZE, n - v0);
    const int tid  = threadIdx.x;
    const int wv   = tid >> 6;      // 0..7
    const int lane = tid & 63;
    if (tid < PSIZE) { lcnt[tid] = 0; lrank[tid] = 0; }
    __syncthreads();
    for (int sg = wv; sg < NGROUP; sg += 8) {
        const int c = min(cnt[sg * NBINP + b], CAP);
        const uint32_t* __restrict__ src = binned + ((size_t)sg * NBIN + b) * CAP;
        for (int i = lane; i < c; i += 64)
            atomicAdd(&lcnt[src[i] >> 20], 1);
    }
    __syncthreads();
    if (tid < PSIZE) {               // 4-wave two-level scan of lcnt
        int v = lcnt[tid];
        int inc = v;
#pragma unroll
        for (int d = 1; d < 64; d <<= 1) {
            int t = __shfl_up(inc, d, 64);
            if (lane >= d) inc += t;
        }
        if (lane == 63) wtot[wv] = inc;
        lofs[tid] = inc - v;
    }
    __syncthreads();
    if (tid < PSIZE) {
        int add = 0;
#pragma unroll
        for (int k = 0; k < 4; ++k) if (k < wv) add += wtot[k];
        lofs[tid] += add;
    }
    __syncthreads();
    const int base = bofs[b];
    for (int sg = wv; sg < NGROUP; sg += 8) {
        const int c = min(cnt[sg * NBINP + b], CAP);
        const uint32_t* __restrict__ src = binned + ((size_t)sg * NBIN + b) * CAP;
        for (int i = lane; i < c; i += 64) {
            uint32_t v = src[i];
            int dl = (int)(v >> 20);
            int rk = atomicAdd(&lrank[dl], 1);
            col[base + lofs[dl] + rk] = (int)(v & 0xFFFFFu);
        }
    }
    if (tid < nn) {
        ofs[v0 + tid]  = base + lofs[tid];
        dinv[v0 + tid] = rsqrtf((float)lcnt[tid] + 1.0f);
    }
    if (tid == 0 && v0 + nn == n) ofs[n] = (int)E;
}

// ---------------------------------------------------------------------------
// hs = bf16( (A @ W) * dinv[:,None] ) — MFMA bf16, LDS-free, split-W hi+lo.
// ---------------------------------------------------------------------------
template<bool AFP32>
__global__ void __launch_bounds__(256) gemm_hs_kernel(
        const void* __restrict__ Ap, const short* __restrict__ Wt,
        const float* __restrict__ dinv, short* __restrict__ hs, int n) {
    const short* __restrict__ Bh = Wt;
    const short* __restrict__ Bl = Wt + HID * HID;
    const int tid = threadIdx.x;
    const int w  = tid >> 6;
    const int l  = tid & 63;
    const int lr = l & 15;
    const int kq = l >> 4;
    const int r0 = blockIdx.x * 128;

    f32x4 acc[8][2] = {};
    const int col0 = w * 32 + lr;
    const int col1 = w * 32 + 16 + lr;

    const float* Af = (const float*)Ap;
    const short* Ab = (const short*)Ap;

#pragma unroll
    for (int ks = 0; ks < 4; ++ks) {
        const int k0 = ks * 32 + kq * 8;
        bf16x8 a[8];
#pragma unroll
        for (int rf = 0; rf < 8; ++rf) {
            int row = r0 + rf * 16 + lr;
            if (row >= n) row = n - 1;
            if (AFP32) {
                const float* ap = Af + (size_t)row * HID + k0;
                float4 f0 = *(const float4*)ap;
                float4 f1 = *(const float4*)(ap + 4);
                bf16x8 tv;
                tv[0] = f2bf(f0.x); tv[1] = f2bf(f0.y); tv[2] = f2bf(f0.z); tv[3] = f2bf(f0.w);
                tv[4] = f2bf(f1.x); tv[5] = f2bf(f1.y); tv[6] = f2bf(f1.z); tv[7] = f2bf(f1.w);
                a[rf] = tv;
            } else {
                a[rf] = *(const bf16x8*)(Ab + (size_t)row * HID + k0);
            }
        }
        bf16x8 bh0 = *(const bf16x8*)(Bh + (size_t)col0 * HID + k0);
        bf16x8 bh1 = *(const bf16x8*)(Bh + (size_t)col1 * HID + k0);
        bf16x8 bl0 = *(const bf16x8*)(Bl + (size_t)col0 * HID + k0);
        bf16x8 bl1 = *(const bf16x8*)(Bl + (size_t)col1 * HID + k0);
#pragma unroll
        for (int rf = 0; rf < 8; ++rf) {
            acc[rf][0] = __builtin_amdgcn_mfma_f32_16x16x32_bf16(a[rf], bh0, acc[rf][0], 0, 0, 0);
            acc[rf][1] = __builtin_amdgcn_mfma_f32_16x16x32_bf16(a[rf], bh1, acc[rf][1], 0, 0, 0);
            acc[rf][0] = __builtin_amdgcn_mfma_f32_16x16x32_bf16(a[rf], bl0, acc[rf][0], 0, 0, 0);
            acc[rf][1] = __builtin_amdgcn_mfma_f32_16x16x32_bf16(a[rf], bl1, acc[rf][1], 0, 0, 0);
        }
    }
#pragma unroll
    for (int rf = 0; rf < 8; ++rf) {
#pragma unroll
        for (int rg = 0; rg < 4; ++rg) {
            int row = r0 + rf * 16 + kq * 4 + rg;
            if (row < n) {
                float dn = dinv[row];
                hs[(size_t)row * HID + col0] = f2bf(acc[rf][0][rg] * dn);
                hs[(size_t)row * HID + col1] = f2bf(acc[rf][1][rg] * dn);
            }
        }
    }
}

// ---------------------------------------------------------------------------
// out[d] = maybe_relu( dinv[d] * (hs[d] + sum_{e->d} hs[src]) + bias )  (bf16)
// One wave per node; 16 lanes per row (dwordx4), 4 rows per gather instr,
// up to 16 rows in flight (ladder 16/4/1). [round-7/10 validated: 66 us]
// ---------------------------------------------------------------------------
__device__ __forceinline__ void acc_add(float* acc, u32x4 v) {
    acc[0] += bflo(v.x); acc[1] += bfhi(v.x);
    acc[2] += bflo(v.y); acc[3] += bfhi(v.y);
    acc[4] += bflo(v.z); acc[5] += bfhi(v.z);
    acc[6] += bflo(v.w); acc[7] += bfhi(v.w);
}

__global__ void __launch_bounds__(256) agg_kernel(
        const short* __restrict__ hs, const float* __restrict__ dinv,
        const int* __restrict__ ofs, const int* __restrict__ col,
        const float* __restrict__ bias, short* __restrict__ out,
        int n, int do_relu) {
    int node = blockIdx.x * 4 + (threadIdx.x >> 6);
    if (node >= n) return;
    const int lane = threadIdx.x & 63;
    const int g    = lane >> 4;      // row-group 0..3
    const int sub  = lane & 15;      // 16B chunk within row
    const u32x4* __restrict__ rows = (const u32x4*)hs;   // one row = 16 u32x4

    float acc[8] = {0.f, 0.f, 0.f, 0.f, 0.f, 0.f, 0.f, 0.f};
    if (g == 0) {                    // self term (hs already *dinv)
        u32x4 sv = rows[(size_t)node * 16 + sub];
        acc_add(acc, sv);
    }
    const int e0 = ofs[node], e1 = ofs[node + 1];
    int e = e0;
    for (; e + 16 <= e1; e += 16) {  // 16 rows in flight
        int c0 = col[e + g];
        int c1 = col[e + 4 + g];
        int c2 = col[e + 8 + g];
        int c3 = col[e + 12 + g];
        u32x4 v0 = rows[(size_t)c0 * 16 + sub];
        u32x4 v1 = rows[(size_t)c1 * 16 + sub];
        u32x4 v2 = rows[(size_t)c2 * 16 + sub];
        u32x4 v3 = rows[(size_t)c3 * 16 + sub];
        acc_add(acc, v0); acc_add(acc, v1); acc_add(acc, v2); acc_add(acc, v3);
    }
    for (; e + 4 <= e1; e += 4) {
        int c0 = col[e + g];
        u32x4 v0 = rows[(size_t)c0 * 16 + sub];
        acc_add(acc, v0);
    }
    if (e + g < e1) {                // tail (<4 edges): one row per live group
        int c0 = col[e + g];
        u32x4 v0 = rows[(size_t)c0 * 16 + sub];
        acc_add(acc, v0);
    }
#pragma unroll
    for (int i = 0; i < 8; ++i) {    // combine the 4 row-groups
        acc[i] += __shfl_xor(acc[i], 16, 64);
        acc[i] += __shfl_xor(acc[i], 32, 64);
    }
    if (g == 0) {
        const float dn = dinv[node];
        float4 b0 = *(const float4*)(bias + 8 * sub);
        float4 b1 = *(const float4*)(bias + 8 * sub + 4);
        float o0 = fmaf(acc[0], dn, b0.x);
        float o1 = fmaf(acc[1], dn, b0.y);
        float o2 = fmaf(acc[2], dn, b0.z);
        float o3 = fmaf(acc[3], dn, b0.w);
        float o4 = fmaf(acc[4], dn, b1.x);
        float o5 = fmaf(acc[5], dn, b1.y);
        float o6 = fmaf(acc[6], dn, b1.z);
        float o7 = fmaf(acc[7], dn, b1.w);
        if (do_relu) {
            o0 = fmaxf(o0, 0.f); o1 = fmaxf(o1, 0.f);
            o2 = fmaxf(o2, 0.f); o3 = fmaxf(o3, 0.f);
            o4 = fmaxf(o4, 0.f); o5 = fmaxf(o5, 0.f);
            o6 = fmaxf(o6, 0.f); o7 = fmaxf(o7, 0.f);
        }
        u32x4 pk;
        pk.x = pk2(o0, o1); pk.y = pk2(o2, o3);
        pk.z = pk2(o4, o5); pk.w = pk2(o6, o7);
        ((u32x4*)out)[(size_t)node * 16 + sub] = pk;
    }
}

// ---------------------------------------------------------------------------
// head: fused mean-pool + MLP (one block per graph)
// ---------------------------------------------------------------------------
__global__ void __launch_bounds__(128) pool_mlp_kernel(
        const short* __restrict__ h, const int* __restrict__ gstart,
        const float* __restrict__ W1, const float* __restrict__ b1,
        const float* __restrict__ W2, const float* __restrict__ b2,
        float* __restrict__ out) {
    __shared__ float p[HID];
    __shared__ float hid[HID];
    int g = blockIdx.x, c = threadIdx.x;
    int s = gstart[g], e = gstart[g + 1];
    float acc = 0.f;
    int i = s;
    for (; i + 4 <= e; i += 4) {
        acc += bf2f(h[(size_t)i * HID + c]) + bf2f(h[(size_t)(i + 1) * HID + c])
             + bf2f(h[(size_t)(i + 2) * HID + c]) + bf2f(h[(size_t)(i + 3) * HID + c]);
    }
    for (; i < e; ++i) acc += bf2f(h[(size_t)i * HID + c]);
    p[c] = acc / fmaxf((float)(e - s), 1.f);
    __syncthreads();
    float a = b1[c];
#pragma unroll 8
    for (int k = 0; k < HID; ++k) a = fmaf(p[k], W1[k * HID + c], a);
    hid[c] = fmaxf(a, 0.f);
    __syncthreads();
    if (c < OUTC) {
        float o = b2[c];
#pragma unroll 8
        for (int k = 0; k < HID; ++k) o = fmaf(hid[k], W2[k * OUTC + c], o);
        out[g * OUTC + c] = o;
    }
}

// ---------------------------------------------------------------------------
extern "C" void kernel_launch(void* const* d_in, const int* in_sizes, int n_in,
                              void* d_out, int out_size, void* d_ws, size_t ws_size,
                              hipStream_t stream) {
    const float* x   = (const float*)d_in[0];
    const int*   ei  = (const int*)d_in[1];
    const int*   bat = (const int*)d_in[2];
    const float* Wc0 = (const float*)d_in[3];
    const float* bc0 = (const float*)d_in[4];
    const float* Wc1 = (const float*)d_in[5];
    const float* bc1 = (const float*)d_in[6];
    const float* Wc2 = (const float*)d_in[7];
    const float* bc2 = (const float*)d_in[8];
    const float* W1  = (const float*)d_in[9];
    const float* b1  = (const float*)d_in[10];
    const float* W2  = (const float*)d_in[11];
    const float* b2  = (const float*)d_in[12];
    float* out = (float*)d_out;

    const int  n = in_sizes[0] / HID;             // 100000 (< 2^20)
    const long E = in_sizes[1] / 2;
    const int  NBIN  = (n + PSIZE - 1) / PSIZE;   // 391
    const int  NBINP = (NBIN + 15) & ~15;         // 400: per-group counters line-aligned
    const int  cntN  = NGROUP * NBINP;

    char* w = (char*)d_ws;
    size_t off = 0;
    auto carve = [&](size_t bytes) {
        void* p = w + off;
        off += (bytes + 255) & ~(size_t)255;
        return p;
    };
    int*   cnt     = (int*)carve((size_t)cntN * 4);
    int*   bofs    = (int*)carve((size_t)(NBIN + 1) * 4);
    int*   ofs     = (int*)carve((size_t)(n + 1) * 4);
    float* dinv    = (float*)carve((size_t)n * 4);
    int*   gstart  = (int*)carve((NGRAPH + 1) * 4);
    int*   col     = (int*)carve((size_t)E * 4);
    short* Wt      = (short*)carve((size_t)3 * 2 * HID * HID * 2);
    short* hs      = (short*)carve((size_t)n * HID * 2);
    short* h       = (short*)carve((size_t)n * HID * 2);
    uint32_t* binned = (uint32_t*)h;  // 64*391*160*4 = 16.0 MB <= 25.6 MB (h), dead before h written

    // prep: 3 wprep blocks + cnt-zero blocks + boundary blocks, one dispatch
    const int nzb = (cntN + 255) / 256;
    const int nbb = (n + 255) / 256;
    prep_kernel<<<3 + nzb + nbb, 256, 0, stream>>>(ei, bat, Wc0, Wc1, Wc2,
                                                   Wt, cnt, cntN, gstart, n);

    bin_scatter_kernel<<<2048, 256, 0, stream>>>(ei, cnt, binned, E, NBIN, NBINP);
    binscan_kernel<<<1, 1024, 0, stream>>>(cnt, bofs, NBIN, NBINP);
    bin_build_kernel<<<NBIN, 512, 0, stream>>>(binned, cnt, bofs, ofs, dinv, col,
                                               n, NBIN, NBINP, E);

    const int gb = (n + 127) / 128;
    const int ab = (n + 3) / 4;
    const size_t WSTRIDE = (size_t)2 * HID * HID;
    // layer 0
    gemm_hs_kernel<true><<<gb, 256, 0, stream>>>(x, Wt, dinv, hs, n);
    agg_kernel<<<ab, 256, 0, stream>>>(hs, dinv, ofs, col, bc0, h, n, 1);
    // layer 1
    gemm_hs_kernel<false><<<gb, 256, 0, stream>>>(h, Wt + WSTRIDE, dinv, hs, n);
    agg_kernel<<<ab, 256, 0, stream>>>(hs, dinv, ofs, col, bc1, h, n, 1);
    // layer 2 (no relu)
    gemm_hs_kernel<false><<<gb, 256, 0, stream>>>(h, Wt + 2 * WSTRIDE, dinv, hs, n);
    agg_kernel<<<ab, 256, 0, stream>>>(hs, dinv, ofs, col, bc2, h, n, 0);

    pool_mlp_kernel<<<NGRAPH, 128, 0, stream>>>(h, gstart, W1, b1, W2, b2, out);
}

// Round 12
// 372.089 us; speedup vs baseline: 1.2561x; 1.1217x over previous
//
#include <hip/hip_runtime.h>
#include <hip/hip_bf16.h>
#include <stdint.h>

#define HID     128
#define OUTC    10
#define NGRAPH  512
#define NGROUP  64         // writer groups (low 3 bits ~ XCD)  [round-6/7 validated]
#define PSIZE   256        // nodes per bin
#define CAP     160        // entries per (group,bin) region (mean 64, ~12 sigma)

using bf16x8 = __attribute__((ext_vector_type(8))) short;
using f32x4  = __attribute__((ext_vector_type(4))) float;
using u32x4  = __attribute__((ext_vector_type(4))) uint32_t;

__device__ __forceinline__ short f2bf(float f) {
    __hip_bfloat16 h = __float2bfloat16(f);
    return *reinterpret_cast<short*>(&h);
}
__device__ __forceinline__ float bf2f(short s) {
    union { uint32_t u; float f; } x; x.u = ((uint32_t)(uint16_t)s) << 16; return x.f;
}
__device__ __forceinline__ float bflo(uint32_t v) {
    union { uint32_t u; float f; } x; x.u = v << 16; return x.f;
}
__device__ __forceinline__ float bfhi(uint32_t v) {
    union { uint32_t u; float f; } x; x.u = v & 0xffff0000u; return x.f;
}
__device__ __forceinline__ uint32_t pk2(float lo, float hi) {
    return (uint32_t)(uint16_t)f2bf(lo) | ((uint32_t)(uint16_t)f2bf(hi) << 16);
}

// Inline int64-vs-int32 layout detection: for int32 edge_index the odd words
// are random node ids (P(all 64 == 0) ~ 0); for little-endian int64 < 2^31
// they are all zero. ei lines are L2-hot after the first wave touches them.
__device__ __forceinline__ int detect_f64(const int* __restrict__ ei) {
    int lane = threadIdx.x & 63;
    int v = ei[2 * lane + 1];
    unsigned long long b = __ballot(v == 0);
    return (b == ~0ULL) ? 1 : 0;
}

__device__ __forceinline__ int fetch_idx(const int* __restrict__ p, long j, int f64) {
    return p[f64 ? (j << 1) : j];
}

// ---------------------------------------------------------------------------
// prep: blocks 0-2 -> weight transpose+split; next blocks -> zero cnt;
// remaining blocks -> graph boundary detection. One dispatch.
// ---------------------------------------------------------------------------
__global__ void __launch_bounds__(256) prep_kernel(
        const int* __restrict__ ei, const int* __restrict__ batch,
        const float* __restrict__ W0, const float* __restrict__ W1,
        const float* __restrict__ W2, short* __restrict__ Wt,
        int* __restrict__ cnt, int cntN, int* __restrict__ gstart, int n) {
    __shared__ float Ws[64][129];
    int bid = blockIdx.x;
    const int tid = threadIdx.x;

    if (bid < 3) {                                   // ---- weight prep (256 thr)
        const float* W = (bid == 0) ? W0 : (bid == 1) ? W1 : W2;
        short* hi = Wt + (size_t)bid * 2 * HID * HID;
        short* lo = hi + HID * HID;
        for (int half = 0; half < 2; ++half) {
            const int kbase = half * 64;
#pragma unroll
            for (int it = 0; it < 8; ++it) {         // 2048 float4 loads
                int idx = (tid + it * 256) * 4;
                int k = idx >> 7, c = idx & 127;
                float4 v = *(const float4*)(W + (size_t)(kbase + k) * HID + c);
                Ws[k][c] = v.x; Ws[k][c + 1] = v.y; Ws[k][c + 2] = v.z; Ws[k][c + 3] = v.w;
            }
            __syncthreads();
            const int k2 = tid & 63;
            const int cb = tid >> 6;                 // 0..3
#pragma unroll
            for (int it = 0; it < 32; ++it) {        // transposed writes
                int c = cb + it * 4;
                float w = Ws[k2][c];
                short h = f2bf(w);
                hi[(size_t)c * HID + kbase + k2] = h;
                lo[(size_t)c * HID + kbase + k2] = f2bf(w - bf2f(h));
            }
            __syncthreads();
        }
        return;
    }
    bid -= 3;
    const int nzb = (cntN + 255) / 256;
    if (bid < nzb) {                                 // ---- zero scatter counters
        int i = bid * 256 + tid;
        if (i < cntN) cnt[i] = 0;
        return;
    }
    bid -= nzb;
    // ---- boundary detection (batch sorted)
    const int f = detect_f64(ei);
    int i = bid * 256 + tid;
    if (i >= n) return;
    int b  = fetch_idx(batch, i, f);
    int bp = (i == 0) ? -1 : fetch_idx(batch, i - 1, f);
    for (int g = bp + 1; g <= b; ++g) gstart[g] = i;
    if (i == n - 1) {
        for (int g = b + 1; g <= NGRAPH; ++g) gstart[g] = n;
    }
}

// ---------------------------------------------------------------------------
// CSR pass A: writer-partitioned bin scatter, 64 writer groups.
// ---------------------------------------------------------------------------
__global__ void __launch_bounds__(256) bin_scatter_kernel(
        const int* __restrict__ ei, int* __restrict__ cnt,
        uint32_t* __restrict__ binned, long E, int NBIN, int NBINP) {
    const int group = blockIdx.x & (NGROUP - 1);
    const int f = detect_f64(ei);
    const long stride = (long)gridDim.x * blockDim.x;
    for (long e = (long)blockIdx.x * blockDim.x + threadIdx.x; e < E; e += stride) {
        int s = fetch_idx(ei, e, f);
        int d = fetch_idx(ei, E + e, f);
        int b = d >> 8;
        int pos = atomicAdd(&cnt[group * NBINP + b], 1);
        if (pos < CAP)
            binned[((size_t)group * NBIN + b) * CAP + pos] =
                (uint32_t)s | ((uint32_t)(d & (PSIZE - 1)) << 20);
    }
}

// ---------------------------------------------------------------------------
// bin totals (sum 64 group counters) + exclusive scan, fused, one block.
// ---------------------------------------------------------------------------
__global__ void __launch_bounds__(1024) binscan_kernel(
        const int* __restrict__ cnt, int* __restrict__ bofs, int NBIN, int NBINP) {
    __shared__ int wsum[16];
    const int tid  = threadIdx.x;
    const int lane = tid & 63;
    const int wid  = tid >> 6;
    int v = 0;
    if (tid < NBIN) {
        for (int g = 0; g < NGROUP; ++g) v += cnt[g * NBINP + tid];
    }
    int inc = v;
#pragma unroll
    for (int d = 1; d < 64; d <<= 1) {
        int t = __shfl_up(inc, d, 64);
        if (lane >= d) inc += t;
    }
    if (lane == 63) wsum[wid] = inc;
    __syncthreads();
    if (wid == 0) {
        int ws = (lane < 16) ? wsum[lane] : 0;
        int winc = ws;
#pragma unroll
        for (int d = 1; d < 16; d <<= 1) {
            int t = __shfl_up(winc, d, 64);
            if (lane >= d) winc += t;
        }
        if (lane < 16) wsum[lane] = winc - ws;
    }
    __syncthreads();
    int excl = wsum[wid] + (inc - v);
    if (tid <= NBIN) bofs[tid] = excl;   // tid >= NBIN: v=0 -> excl = grand total
}

// ---------------------------------------------------------------------------
// CSR pass B: one block per bin; LDS histogram -> scan -> scatter; ofs + dinv.
// ---------------------------------------------------------------------------
__global__ void __launch_bounds__(512) bin_build_kernel(
        const uint32_t* __restrict__ binned, const int* __restrict__ cnt,
        const int* __restrict__ bofs, int* __restrict__ ofs,
        float* __restrict__ dinv, int* __restrict__ col,
        int n, int NBIN, int NBINP, long E) {
    __shared__ int lcnt[PSIZE];
    __shared__ int lofs[PSIZE];
    __shared__ int lrank[PSIZE];
    __shared__ int wtot[4];
    const int b    = blockIdx.x;
    const int v0   = b * PSIZE;
    const int nn   = min(PSIZE, n - v0);
    const int tid  = threadIdx.x;
    const int wv   = tid >> 6;      // 0..7
    const int lane = tid & 63;
    if (tid < PSIZE) { lcnt[tid] = 0; lrank[tid] = 0; }
    __syncthreads();
    for (int sg = wv; sg < NGROUP; sg += 8) {
        const int c = min(cnt[sg * NBINP + b], CAP);
        const uint32_t* __restrict__ src = binned + ((size_t)sg * NBIN + b) * CAP;
        for (int i = lane; i < c; i += 64)
            atomicAdd(&lcnt[src[i] >> 20], 1);
    }
    __syncthreads();
    if (tid < PSIZE) {               // 4-wave two-level scan of lcnt
        int v = lcnt[tid];
        int inc = v;
#pragma unroll
        for (int d = 1; d < 64; d <<= 1) {
            int t = __shfl_up(inc, d, 64);
            if (lane >= d) inc += t;
        }
        if (lane == 63) wtot[wv] = inc;
        lofs[tid] = inc - v;
    }
    __syncthreads();
    if (tid < PSIZE) {
        int add = 0;
#pragma unroll
        for (int k = 0; k < 4; ++k) if (k < wv) add += wtot[k];
        lofs[tid] += add;
    }
    __syncthreads();
    const int base = bofs[b];
    for (int sg = wv; sg < NGROUP; sg += 8) {
        const int c = min(cnt[sg * NBINP + b], CAP);
        const uint32_t* __restrict__ src = binned + ((size_t)sg * NBIN + b) * CAP;
        for (int i = lane; i < c; i += 64) {
            uint32_t v = src[i];
            int dl = (int)(v >> 20);
            int rk = atomicAdd(&lrank[dl], 1);
            col[base + lofs[dl] + rk] = (int)(v & 0xFFFFFu);
        }
    }
    if (tid < nn) {
        ofs[v0 + tid]  = base + lofs[tid];
        dinv[v0 + tid] = rsqrtf((float)lcnt[tid] + 1.0f);
    }
    if (tid == 0 && v0 + nn == n) ofs[n] = (int)E;
}

// ---------------------------------------------------------------------------
// hs = bf16( (A @ W) * dinv[:,None] ) — MFMA bf16, split-W hi+lo.
// A tile staged ONCE in LDS (32 KB), chunk-XOR swizzle (chunk ^= row&15) on
// both the staged write and the fragment read -> even bank distribution and
// 4x less global A traffic (all 4 waves used to re-read the same rows).
// ---------------------------------------------------------------------------
template<bool AFP32>
__global__ void __launch_bounds__(256) gemm_hs_kernel(
        const void* __restrict__ Ap, const short* __restrict__ Wt,
        const float* __restrict__ dinv, short* __restrict__ hs, int n) {
    __shared__ __attribute__((aligned(16))) short As[128 * 128];  // 32 KB
    const short* __restrict__ Bh = Wt;
    const short* __restrict__ Bl = Wt + HID * HID;
    const int tid = threadIdx.x;
    const int w  = tid >> 6;
    const int l  = tid & 63;
    const int lr = l & 15;
    const int kq = l >> 4;
    const int r0 = blockIdx.x * 128;

    const float* Af = (const float*)Ap;
    const short* Ab = (const short*)Ap;

    // ---- stage A tile (128 rows x 16 chunks of 16B), swizzled
#pragma unroll
    for (int it = 0; it < 8; ++it) {
        int ci  = tid + it * 256;        // chunk index 0..2047
        int row = ci >> 4, c = ci & 15;
        int rg  = r0 + row; if (rg >= n) rg = n - 1;
        bf16x8 tv;
        if (AFP32) {
            const float* ap = Af + (size_t)rg * HID + c * 8;
            float4 f0 = *(const float4*)ap;
            float4 f1 = *(const float4*)(ap + 4);
            tv[0] = f2bf(f0.x); tv[1] = f2bf(f0.y); tv[2] = f2bf(f0.z); tv[3] = f2bf(f0.w);
            tv[4] = f2bf(f1.x); tv[5] = f2bf(f1.y); tv[6] = f2bf(f1.z); tv[7] = f2bf(f1.w);
        } else {
            tv = *(const bf16x8*)(Ab + (size_t)rg * HID + c * 8);
        }
        *(bf16x8*)(As + row * 128 + ((c ^ (row & 15)) << 3)) = tv;
    }
    __syncthreads();

    f32x4 acc[8][2] = {};
    const int col0 = w * 32 + lr;
    const int col1 = w * 32 + 16 + lr;

#pragma unroll
    for (int ks = 0; ks < 4; ++ks) {
        const int k0 = ks * 32 + kq * 8;
        bf16x8 a[8];
#pragma unroll
        for (int rf = 0; rf < 8; ++rf) {
            int row = rf * 16 + lr;      // row & 15 == lr
            a[rf] = *(const bf16x8*)(As + row * 128 + (((ks * 4 + kq) ^ lr) << 3));
        }
        bf16x8 bh0 = *(const bf16x8*)(Bh + (size_t)col0 * HID + k0);
        bf16x8 bh1 = *(const bf16x8*)(Bh + (size_t)col1 * HID + k0);
        bf16x8 bl0 = *(const bf16x8*)(Bl + (size_t)col0 * HID + k0);
        bf16x8 bl1 = *(const bf16x8*)(Bl + (size_t)col1 * HID + k0);
#pragma unroll
        for (int rf = 0; rf < 8; ++rf) {
            acc[rf][0] = __builtin_amdgcn_mfma_f32_16x16x32_bf16(a[rf], bh0, acc[rf][0], 0, 0, 0);
            acc[rf][1] = __builtin_amdgcn_mfma_f32_16x16x32_bf16(a[rf], bh1, acc[rf][1], 0, 0, 0);
            acc[rf][0] = __builtin_amdgcn_mfma_f32_16x16x32_bf16(a[rf], bl0, acc[rf][0], 0, 0, 0);
            acc[rf][1] = __builtin_amdgcn_mfma_f32_16x16x32_bf16(a[rf], bl1, acc[rf][1], 0, 0, 0);
        }
    }
#pragma unroll
    for (int rf = 0; rf < 8; ++rf) {
#pragma unroll
        for (int rg = 0; rg < 4; ++rg) {
            int row = r0 + rf * 16 + kq * 4 + rg;
            if (row < n) {
                float dn = dinv[row];
                hs[(size_t)row * HID + col0] = f2bf(acc[rf][0][rg] * dn);
                hs[(size_t)row * HID + col1] = f2bf(acc[rf][1][rg] * dn);
            }
        }
    }
}

// ---------------------------------------------------------------------------
// out[d] = maybe_relu( dinv[d] * (hs[d] + sum_{e->d} hs[src]) + bias )  (bf16)
// One wave per node; 16 lanes per row (dwordx4), 4 rows per gather instr,
// up to 16 rows in flight (ladder 16/4/1). [round-7/10 validated: 66 us]
// ---------------------------------------------------------------------------
__device__ __forceinline__ void acc_add(float* acc, u32x4 v) {
    acc[0] += bflo(v.x); acc[1] += bfhi(v.x);
    acc[2] += bflo(v.y); acc[3] += bfhi(v.y);
    acc[4] += bflo(v.z); acc[5] += bfhi(v.z);
    acc[6] += bflo(v.w); acc[7] += bfhi(v.w);
}

__global__ void __launch_bounds__(256) agg_kernel(
        const short* __restrict__ hs, const float* __restrict__ dinv,
        const int* __restrict__ ofs, const int* __restrict__ col,
        const float* __restrict__ bias, short* __restrict__ out,
        int n, int do_relu) {
    int node = blockIdx.x * 4 + (threadIdx.x >> 6);
    if (node >= n) return;
    const int lane = threadIdx.x & 63;
    const int g    = lane >> 4;      // row-group 0..3
    const int sub  = lane & 15;      // 16B chunk within row
    const u32x4* __restrict__ rows = (const u32x4*)hs;   // one row = 16 u32x4

    float acc[8] = {0.f, 0.f, 0.f, 0.f, 0.f, 0.f, 0.f, 0.f};
    if (g == 0) {                    // self term (hs already *dinv)
        u32x4 sv = rows[(size_t)node * 16 + sub];
        acc_add(acc, sv);
    }
    const int e0 = ofs[node], e1 = ofs[node + 1];
    int e = e0;
    for (; e + 16 <= e1; e += 16) {  // 16 rows in flight
        int c0 = col[e + g];
        int c1 = col[e + 4 + g];
        int c2 = col[e + 8 + g];
        int c3 = col[e + 12 + g];
        u32x4 v0 = rows[(size_t)c0 * 16 + sub];
        u32x4 v1 = rows[(size_t)c1 * 16 + sub];
        u32x4 v2 = rows[(size_t)c2 * 16 + sub];
        u32x4 v3 = rows[(size_t)c3 * 16 + sub];
        acc_add(acc, v0); acc_add(acc, v1); acc_add(acc, v2); acc_add(acc, v3);
    }
    for (; e + 4 <= e1; e += 4) {
        int c0 = col[e + g];
        u32x4 v0 = rows[(size_t)c0 * 16 + sub];
        acc_add(acc, v0);
    }
    if (e + g < e1) {                // tail (<4 edges): one row per live group
        int c0 = col[e + g];
        u32x4 v0 = rows[(size_t)c0 * 16 + sub];
        acc_add(acc, v0);
    }
#pragma unroll
    for (int i = 0; i < 8; ++i) {    // combine the 4 row-groups
        acc[i] += __shfl_xor(acc[i], 16, 64);
        acc[i] += __shfl_xor(acc[i], 32, 64);
    }
    if (g == 0) {
        const float dn = dinv[node];
        float4 b0 = *(const float4*)(bias + 8 * sub);
        float4 b1 = *(const float4*)(bias + 8 * sub + 4);
        float o0 = fmaf(acc[0], dn, b0.x);
        float o1 = fmaf(acc[1], dn, b0.y);
        float o2 = fmaf(acc[2], dn, b0.z);
        float o3 = fmaf(acc[3], dn, b0.w);
        float o4 = fmaf(acc[4], dn, b1.x);
        float o5 = fmaf(acc[5], dn, b1.y);
        float o6 = fmaf(acc[6], dn, b1.z);
        float o7 = fmaf(acc[7], dn, b1.w);
        if (do_relu) {
            o0 = fmaxf(o0, 0.f); o1 = fmaxf(o1, 0.f);
            o2 = fmaxf(o2, 0.f); o3 = fmaxf(o3, 0.f);
            o4 = fmaxf(o4, 0.f); o5 = fmaxf(o5, 0.f);
            o6 = fmaxf(o6, 0.f); o7 = fmaxf(o7, 0.f);
        }
        u32x4 pk;
        pk.x = pk2(o0, o1); pk.y = pk2(o2, o3);
        pk.z = pk2(o4, o5); pk.w = pk2(o6, o7);
        ((u32x4*)out)[(size_t)node * 16 + sub] = pk;
    }
}

// ---------------------------------------------------------------------------
// head: fused mean-pool + MLP (one block per graph)
// ---------------------------------------------------------------------------
__global__ void __launch_bounds__(128) pool_mlp_kernel(
        const short* __restrict__ h, const int* __restrict__ gstart,
        const float* __restrict__ W1, const float* __restrict__ b1,
        const float* __restrict__ W2, const float* __restrict__ b2,
        float* __restrict__ out) {
    __shared__ float p[HID];
    __shared__ float hid[HID];
    int g = blockIdx.x, c = threadIdx.x;
    int s = gstart[g], e = gstart[g + 1];
    float acc = 0.f;
    int i = s;
    for (; i + 4 <= e; i += 4) {
        acc += bf2f(h[(size_t)i * HID + c]) + bf2f(h[(size_t)(i + 1) * HID + c])
             + bf2f(h[(size_t)(i + 2) * HID + c]) + bf2f(h[(size_t)(i + 3) * HID + c]);
    }
    for (; i < e; ++i) acc += bf2f(h[(size_t)i * HID + c]);
    p[c] = acc / fmaxf((float)(e - s), 1.f);
    __syncthreads();
    float a = b1[c];
#pragma unroll 8
    for (int k = 0; k < HID; ++k) a = fmaf(p[k], W1[k * HID + c], a);
    hid[c] = fmaxf(a, 0.f);
    __syncthreads();
    if (c < OUTC) {
        float o = b2[c];
#pragma unroll 8
        for (int k = 0; k < HID; ++k) o = fmaf(hid[k], W2[k * OUTC + c], o);
        out[g * OUTC + c] = o;
    }
}

// ---------------------------------------------------------------------------
extern "C" void kernel_launch(void* const* d_in, const int* in_sizes, int n_in,
                              void* d_out, int out_size, void* d_ws, size_t ws_size,
                              hipStream_t stream) {
    const float* x   = (const float*)d_in[0];
    const int*   ei  = (const int*)d_in[1];
    const int*   bat = (const int*)d_in[2];
    const float* Wc0 = (const float*)d_in[3];
    const float* bc0 = (const float*)d_in[4];
    const float* Wc1 = (const float*)d_in[5];
    const float* bc1 = (const float*)d_in[6];
    const float* Wc2 = (const float*)d_in[7];
    const float* bc2 = (const float*)d_in[8];
    const float* W1  = (const float*)d_in[9];
    const float* b1  = (const float*)d_in[10];
    const float* W2  = (const float*)d_in[11];
    const float* b2  = (const float*)d_in[12];
    float* out = (float*)d_out;

    const int  n = in_sizes[0] / HID;             // 100000 (< 2^20)
    const long E = in_sizes[1] / 2;
    const int  NBIN  = (n + PSIZE - 1) / PSIZE;   // 391
    const int  NBINP = (NBIN + 15) & ~15;         // 400: per-group counters line-aligned
    const int  cntN  = NGROUP * NBINP;

    char* w = (char*)d_ws;
    size_t off = 0;
    auto carve = [&](size_t bytes) {
        void* p = w + off;
        off += (bytes + 255) & ~(size_t)255;
        return p;
    };
    int*   cnt     = (int*)carve((size_t)cntN * 4);
    int*   bofs    = (int*)carve((size_t)(NBIN + 1) * 4);
    int*   ofs     = (int*)carve((size_t)(n + 1) * 4);
    float* dinv    = (float*)carve((size_t)n * 4);
    int*   gstart  = (int*)carve((NGRAPH + 1) * 4);
    int*   col     = (int*)carve((size_t)E * 4);
    short* Wt      = (short*)carve((size_t)3 * 2 * HID * HID * 2);
    short* hs      = (short*)carve((size_t)n * HID * 2);
    short* h       = (short*)carve((size_t)n * HID * 2);
    uint32_t* binned = (uint32_t*)h;  // 64*391*160*4 = 16.0 MB <= 25.6 MB (h), dead before h written

    // prep: 3 wprep blocks + cnt-zero blocks + boundary blocks, one dispatch
    const int nzb = (cntN + 255) / 256;
    const int nbb = (n + 255) / 256;
    prep_kernel<<<3 + nzb + nbb, 256, 0, stream>>>(ei, bat, Wc0, Wc1, Wc2,
                                                   Wt, cnt, cntN, gstart, n);

    bin_scatter_kernel<<<2048, 256, 0, stream>>>(ei, cnt, binned, E, NBIN, NBINP);
    binscan_kernel<<<1, 1024, 0, stream>>>(cnt, bofs, NBIN, NBINP);
    bin_build_kernel<<<NBIN, 512, 0, stream>>>(binned, cnt, bofs, ofs, dinv, col,
                                               n, NBIN, NBINP, E);

    const int gb = (n + 127) / 128;
    const int ab = (n + 3) / 4;
    const size_t WSTRIDE = (size_t)2 * HID * HID;
    // layer 0
    gemm_hs_kernel<true><<<gb, 256, 0, stream>>>(x, Wt, dinv, hs, n);
    agg_kernel<<<ab, 256, 0, stream>>>(hs, dinv, ofs, col, bc0, h, n, 1);
    // layer 1
    gemm_hs_kernel<false><<<gb, 256, 0, stream>>>(h, Wt + WSTRIDE, dinv, hs, n);
    agg_kernel<<<ab, 256, 0, stream>>>(hs, dinv, ofs, col, bc1, h, n, 1);
    // layer 2 (no relu)
    gemm_hs_kernel<false><<<gb, 256, 0, stream>>>(h, Wt + 2 * WSTRIDE, dinv, hs, n);
    agg_kernel<<<ab, 256, 0, stream>>>(hs, dinv, ofs, col, bc2, h, n, 0);

    pool_mlp_kernel<<<NGRAPH, 128, 0, stream>>>(h, gstart, W1, b1, W2, b2, out);
}